// Round 6
// baseline (1872.067 us; speedup 1.0000x reference)
//
#include <hip/hip_runtime.h>
#include <hip/hip_bf16.h>

// B=4, T=1024, E=1024, ATT=64, NH=16, AH=1024. M = B*T = 4096, K = N = 1024.
// Pipeline: cast x->bf16; transpose+cast W{q,k,v,o} -> [N][K] bf16;
//           fused QKV MFMA GEMM (128x128, global_load_lds, K-slab pre-scaled
//           by 0.125*log2e); register-path MFMA flash attention (S^T trick:
//           P never touches LDS); O-proj GEMM (64x128 -> 512 blocks).

typedef __bf16 bf16_t;
typedef bf16_t bf16x8 __attribute__((ext_vector_type(8)));
typedef short  s16x4 __attribute__((ext_vector_type(4)));
typedef float  f32x4 __attribute__((ext_vector_type(4)));

#define SCALE_LOG2E 0.18033688011112042f  /* 0.125 * log2(e) */

__device__ __forceinline__ void async16(const bf16_t* g, void* l) {
    __builtin_amdgcn_global_load_lds(
        (const __attribute__((address_space(1))) unsigned int*)g,
        (__attribute__((address_space(3))) unsigned int*)l,
        16, 0, 0);
}

// ---------- cast fp32 -> bf16, 8 elems/thread ----------
__global__ __launch_bounds__(256) void cast_f32_bf16(
    const float* __restrict__ in, bf16_t* __restrict__ out, int n8)
{
    int i = blockIdx.x * 256 + threadIdx.x;
    if (i >= n8) return;
    const float4* p = (const float4*)in + (size_t)i * 2;
    float4 a = p[0], b = p[1];
    bf16x8 o;
    o[0] = (bf16_t)a.x; o[1] = (bf16_t)a.y; o[2] = (bf16_t)a.z; o[3] = (bf16_t)a.w;
    o[4] = (bf16_t)b.x; o[5] = (bf16_t)b.y; o[6] = (bf16_t)b.z; o[7] = (bf16_t)b.w;
    *((bf16x8*)out + i) = o;
}

// ---------- transpose + cast: W [1024][1024] fp32 [K][N] -> [N][K] bf16 ----------
__global__ __launch_bounds__(256) void transpose_cast(
    const float* __restrict__ W0, const float* __restrict__ W1,
    const float* __restrict__ W2, const float* __restrict__ W3,
    bf16_t* __restrict__ out)
{
    __shared__ float st[32][33];
    const float* W = (blockIdx.z == 0) ? W0 : (blockIdx.z == 1) ? W1
                   : (blockIdx.z == 2) ? W2 : W3;
    bf16_t* o = out + (size_t)blockIdx.z * 1024 * 1024;
    const int n0 = blockIdx.x * 32, k0 = blockIdx.y * 32;
    const int t = threadIdx.x;
    const int r = t >> 3, c4 = (t & 7) * 4;
    float4 v = *(const float4*)(W + (size_t)(k0 + r) * 1024 + n0 + c4);
    st[r][c4 + 0] = v.x; st[r][c4 + 1] = v.y; st[r][c4 + 2] = v.z; st[r][c4 + 3] = v.w;
    __syncthreads();
    bf16_t tmp[4] __attribute__((aligned(8)));
    #pragma unroll
    for (int i = 0; i < 4; ++i) tmp[i] = (bf16_t)st[c4 + i][r];
    *(uint2*)(o + (size_t)(n0 + r) * 1024 + k0 + c4) = *(const uint2*)tmp;
}

// ---------- MFMA GEMM: C = A[M,1024] @ Bt[N,1024]^T + bias ----------
// (unchanged from round 5; see comments there)
template<bool FUSED, int MT>
__global__ __launch_bounds__(256, 3) void gemm_glds(
    const bf16_t* __restrict__ A, const bf16_t* __restrict__ Bt,
    const float* __restrict__ b0, const float* __restrict__ b1,
    const float* __restrict__ b2,
    bf16_t* __restrict__ Qo, bf16_t* __restrict__ Ko, bf16_t* __restrict__ Vo,
    float* __restrict__ Fo)
{
    const int K = 1024;
    __shared__ __align__(16) bf16_t As[MT * 32];
    __shared__ __align__(16) bf16_t Bs[128 * 32];

    constexpr int NTPW = (MT == 128) ? 4 : 2;
    constexpr int JA   = MT / 64;

    const int tid  = threadIdx.x;
    const int wave = tid >> 6;
    const int lane = tid & 63;
    const int quad = lane >> 4;
    const int l16  = lane & 15;
    const int m0 = blockIdx.y * MT;
    const int n0 = blockIdx.x * 128;
    const int wm = (MT == 128) ? (wave >> 1) * 64 : 0;
    const int wn = (MT == 128) ? (wave & 1) * 64 : wave * 32;

    int goffA[JA], goffB[2];
    #pragma unroll
    for (int j = 0; j < JA; ++j) {
        const int row = j * 64 + (tid >> 2);
        const int cl  = (tid & 3) ^ ((row >> 1) & 3);
        goffA[j] = (m0 + row) * K + cl * 8;
    }
    #pragma unroll
    for (int j = 0; j < 2; ++j) {
        const int row = j * 64 + (tid >> 2);
        const int cl  = (tid & 3) ^ ((row >> 1) & 3);
        goffB[j] = (n0 + row) * K + cl * 8;
    }
    const int ldsoff = wave * 1024;

    f32x4 acc[4][NTPW] = {};
    const int sw = (l16 >> 1) & 3;

    for (int k0 = 0; k0 < K; k0 += 32) {
        #pragma unroll
        for (int j = 0; j < JA; ++j)
            async16(A + goffA[j] + k0, (char*)As + j * 4096 + ldsoff);
        #pragma unroll
        for (int j = 0; j < 2; ++j)
            async16(Bt + goffB[j] + k0, (char*)Bs + j * 4096 + ldsoff);
        __syncthreads();

        bf16x8 af[4], bfr[NTPW];
        #pragma unroll
        for (int mt = 0; mt < 4; ++mt)
            af[mt] = *(const bf16x8*)(&As[(wm + mt * 16 + l16) * 32 + (quad ^ sw) * 8]);
        #pragma unroll
        for (int nt = 0; nt < NTPW; ++nt)
            bfr[nt] = *(const bf16x8*)(&Bs[(wn + nt * 16 + l16) * 32 + (quad ^ sw) * 8]);
        #pragma unroll
        for (int mt = 0; mt < 4; ++mt)
            #pragma unroll
            for (int nt = 0; nt < NTPW; ++nt)
                acc[mt][nt] = __builtin_amdgcn_mfma_f32_16x16x32_bf16(
                    af[mt], bfr[nt], acc[mt][nt], 0, 0, 0);
        __syncthreads();
    }

    if (FUSED) {
        const int sel = n0 >> 10;
        const float* bias = (sel == 0) ? b0 : (sel == 1) ? b1 : b2;
        bf16_t* Cout      = (sel == 0) ? Qo : (sel == 1) ? Ko : Vo;
        const float scl   = (sel == 1) ? SCALE_LOG2E : 1.0f;
        const int nb = n0 & 1023;
        #pragma unroll
        for (int nt = 0; nt < NTPW; ++nt) {
            const int n = nb + wn + nt * 16 + l16;
            const float bb = bias[n];
            #pragma unroll
            for (int mt = 0; mt < 4; ++mt)
                #pragma unroll
                for (int i = 0; i < 4; ++i) {
                    const int m = m0 + wm + mt * 16 + quad * 4 + i;
                    Cout[(size_t)m * 1024 + n] = (bf16_t)((acc[mt][nt][i] + bb) * scl);
                }
        }
    } else {
        #pragma unroll
        for (int nt = 0; nt < NTPW; ++nt) {
            const int n = n0 + wn + nt * 16 + l16;
            const float bb = b0[n];
            #pragma unroll
            for (int mt = 0; mt < 4; ++mt)
                #pragma unroll
                for (int i = 0; i < 4; ++i) {
                    const int m = m0 + wm + mt * 16 + quad * 4 + i;
                    Fo[(size_t)m * 1024 + n] = acc[mt][nt][i] + bb;
                }
        }
    }
}

// ---------- MFMA flash attention, register-path P (no LDS round-trip) ----------
// Grid 1024: (head hd = bx>>2, q-chunk qc = bx&3). 256 thr = 4 waves, wave
// owns 64 q rows (4 q-subs of 16). K pre-scaled by 0.125*log2e.
// Trick: compute S^T = K.Q^T (mfma 16x16x32, swap operands). C-layout of S^T
// gives lane: q = l16, keys = quad*4+i -- EXACTLY the B-operand layout of
// v_mfma_f32_16x16x16_bf16 (B[n=l16][k=quad*4+j]). So p = exp2(s) is packed
// in-register (2 v_perm) and fed straight into Z^T = V^T.P^T and l = 1.P^T.
// P never touches LDS -> kills the write->lgkmcnt(0)->read serial chain and
// all its bank conflicts. Only V^T is staged (4.6 KB, double-buffered,
// 1 barrier/tile). Z^T D-layout (q=l16, d=quad*4+i) -> 8B store per q-sub.
__global__ __launch_bounds__(256, 4) void attn_kernel(
    const bf16_t* __restrict__ Q, const bf16_t* __restrict__ K,
    const bf16_t* __restrict__ V, bf16_t* __restrict__ Z)
{
    __shared__ __align__(16) bf16_t Vt[2][16 * 72];   // [buf][d][key], stride 72

    const int tid  = threadIdx.x;
    const int wave = tid >> 6;
    const int lane = tid & 63;
    const int quad = lane >> 4;
    const int l16  = lane & 15;
    const int hd = blockIdx.x >> 2;
    const int qc = blockIdx.x & 3;
    const int a = hd >> 2, b = hd & 3;
    const int col0 = a * 16;
    const int qbase = qc * 256 + wave * 64;

    // Q as B-operand of S^T: B[n=q=l16][k=d=quad*8+j], quads 2,3 zero (d<16)
    bf16x8 qf[4] = {};
    if (quad < 2) {
        #pragma unroll
        for (int qs = 0; qs < 4; ++qs)
            qf[qs] = *(const bf16x8*)(Q +
                (size_t)(b * 1024 + qbase + qs * 16 + l16) * 1024 + col0 + quad * 8);
    }

    // K as A-operand of S^T: A[m=key=l16][k=d=quad*8+j], double-buffered regs
    const bf16_t* Kp = K + (size_t)(b * 1024 + l16) * 1024 + col0 + quad * 8;
    bf16x8 kf[2][4] = {};
    if (quad < 2) {
        #pragma unroll
        for (int kt = 0; kt < 4; ++kt)
            kf[0][kt] = *(const bf16x8*)(Kp + (size_t)(kt * 16) * 1024);
    }

    // V staging: thread (r = tid>>2, dq = (tid&3)*4) loads V[r][dq..dq+3],
    // writes transposed Vt[dq+ii][r].
    const int r  = tid >> 2;
    const int dq = (tid & 3) * 4;
    const bf16_t* Vp = V + (size_t)(b * 1024 + r) * 1024 + col0 + dq;

    uint2 vv = *(const uint2*)Vp;          // tile 0
    {
        bf16_t t4[4] __attribute__((aligned(8)));
        *(uint2*)t4 = vv;
        #pragma unroll
        for (int ii = 0; ii < 4; ++ii)
            Vt[0][(dq + ii) * 72 + r] = t4[ii];
    }
    vv = *(const uint2*)(Vp + (size_t)64 * 1024);   // prefetch tile 1
    __syncthreads();

    const s16x4 ones = { 0x3F80, 0x3F80, 0x3F80, 0x3F80 };  // bf16 1.0 x4

    f32x4 zacc[4] = {};
    f32x4 lacc[4] = {};

    for (int j = 0; j < 16; ++j) {
        const int cur = j & 1, nxt = cur ^ 1;

        // prefetch K frags for tile j+1
        if (j < 15 && quad < 2) {
            #pragma unroll
            for (int kt = 0; kt < 4; ++kt)
                kf[nxt][kt] = *(const bf16x8*)(Kp + (size_t)((j + 1) * 64 + kt * 16) * 1024);
        }
        // stage V tile j+1 into Vt[nxt]; prefetch V tile j+2
        if (j < 15) {
            bf16_t t4[4] __attribute__((aligned(8)));
            *(uint2*)t4 = vv;
            #pragma unroll
            for (int ii = 0; ii < 4; ++ii)
                Vt[nxt][(dq + ii) * 72 + r] = t4[ii];
            if (j < 14)
                vv = *(const uint2*)(Vp + (size_t)((j + 2) * 64) * 1024);
        }

        // compute on tile j
        #pragma unroll
        for (int kt = 0; kt < 4; ++kt) {
            // V^T A-frag: A[m=d=l16][k=key=quad*4+jj]
            const s16x4 vfrag = __builtin_bit_cast(s16x4,
                *(const uint2*)(&Vt[cur][l16 * 72 + kt * 16 + quad * 4]));
            #pragma unroll
            for (int qs = 0; qs < 4; ++qs) {
                f32x4 zc = {0.f, 0.f, 0.f, 0.f};
                f32x4 s = __builtin_amdgcn_mfma_f32_16x16x32_bf16(
                    kf[cur][kt], qf[qs], zc, 0, 0, 0);
                unsigned int u0 = __builtin_bit_cast(unsigned int, exp2f(s[0])) + 0x8000u;
                unsigned int u1 = __builtin_bit_cast(unsigned int, exp2f(s[1])) + 0x8000u;
                unsigned int u2 = __builtin_bit_cast(unsigned int, exp2f(s[2])) + 0x8000u;
                unsigned int u3 = __builtin_bit_cast(unsigned int, exp2f(s[3])) + 0x8000u;
                uint2 w;
                w.x = __builtin_amdgcn_perm(u1, u0, 0x07060302u);  // [bf16(p1)|bf16(p0)]
                w.y = __builtin_amdgcn_perm(u3, u2, 0x07060302u);
                const s16x4 pfrag = __builtin_bit_cast(s16x4, w);
                zacc[qs] = __builtin_amdgcn_mfma_f32_16x16x16bf16_1k(
                    vfrag, pfrag, zacc[qs], 0, 0, 0);
                lacc[qs] = __builtin_amdgcn_mfma_f32_16x16x16bf16_1k(
                    ones, pfrag, lacc[qs], 0, 0, 0);
            }
        }
        __syncthreads();
    }

    // epilogue: lane holds Z^T[d=quad*4+i][q=l16] and l[q] in lacc[qs][*]
    #pragma unroll
    for (int qs = 0; qs < 4; ++qs) {
        const float inv = 1.0f / lacc[qs][0];
        const int q = qbase + qs * 16 + l16;
        bf16_t o4[4] __attribute__((aligned(8)));
        #pragma unroll
        for (int i = 0; i < 4; ++i) o4[i] = (bf16_t)(zacc[qs][i] * inv);
        *(uint2*)(Z + ((size_t)hd * 1024 + q) * 16 + quad * 4) = *(const uint2*)o4;
    }
}

extern "C" void kernel_launch(void* const* d_in, const int* in_sizes, int n_in,
                              void* d_out, int out_size, void* d_ws, size_t ws_size,
                              hipStream_t stream) {
    const float* x  = (const float*)d_in[0];
    const float* Wq = (const float*)d_in[1];
    const float* bq = (const float*)d_in[2];
    const float* Wk = (const float*)d_in[3];
    const float* bk = (const float*)d_in[4];
    const float* Wv = (const float*)d_in[5];
    const float* bv = (const float*)d_in[6];
    const float* Wo = (const float*)d_in[7];
    const float* bo = (const float*)d_in[8];
    float* out = (float*)d_out;

    char* ws = (char*)d_ws;
    bf16_t* x_bf = (bf16_t*)(ws);
    bf16_t* Wt   = (bf16_t*)(ws + (8u << 20));   // q|k|v|o slabs, contiguous
    bf16_t* Qb   = (bf16_t*)(ws + (16u << 20));
    bf16_t* Kb   = (bf16_t*)(ws + (24u << 20));
    bf16_t* Vb   = (bf16_t*)(ws + (32u << 20));
    bf16_t* Zb   = (bf16_t*)(ws + (40u << 20));
    bf16_t* WtO  = Wt + (size_t)3 * 1024 * 1024;

    cast_f32_bf16<<<dim3(2048), dim3(256), 0, stream>>>(x, x_bf, 524288);
    transpose_cast<<<dim3(32, 32, 4), dim3(256), 0, stream>>>(Wq, Wk, Wv, Wo, Wt);

    // fused QKV: Bt = [3072][1024] (Wq|Wk|Wv)
    gemm_glds<true, 128><<<dim3(24, 32), dim3(256), 0, stream>>>(
        x_bf, Wt, bq, bk, bv, Qb, Kb, Vb, nullptr);

    attn_kernel<<<dim3(1024), dim3(256), 0, stream>>>(Qb, Kb, Vb, Zb);

    // O-projection: 64x128 tiles -> 512 blocks (2/CU)
    gemm_glds<false, 64><<<dim3(8, 64), dim3(256), 0, stream>>>(
        Zb, WtO, bo, nullptr, nullptr, nullptr, nullptr, nullptr, out);
}

// Round 7
// 222.712 us; speedup vs baseline: 8.4058x; 8.4058x over previous
//
#include <hip/hip_runtime.h>
#include <hip/hip_bf16.h>

// B=4, T=1024, E=1024, ATT=64, NH=16, AH=1024. M = B*T = 4096, K = N = 1024.
// Pipeline: cast x->bf16; transpose+cast W{q,k,v,o} -> [N][K] bf16;
//           fused QKV MFMA GEMM (128x128, global_load_lds, K-slab pre-scaled
//           by 0.125*log2e); register-path MFMA flash attention (S^T trick:
//           P never touches LDS); O-proj GEMM (64x128 -> 512 blocks).

typedef __bf16 bf16_t;
typedef bf16_t bf16x8 __attribute__((ext_vector_type(8)));
typedef short  s16x4 __attribute__((ext_vector_type(4)));
typedef float  f32x4 __attribute__((ext_vector_type(4)));

#define SCALE_LOG2E 0.18033688011112042f  /* 0.125 * log2(e) */

__device__ __forceinline__ void async16(const bf16_t* g, void* l) {
    __builtin_amdgcn_global_load_lds(
        (const __attribute__((address_space(1))) unsigned int*)g,
        (__attribute__((address_space(3))) unsigned int*)l,
        16, 0, 0);
}

// ---------- cast fp32 -> bf16, 8 elems/thread ----------
__global__ __launch_bounds__(256) void cast_f32_bf16(
    const float* __restrict__ in, bf16_t* __restrict__ out, int n8)
{
    int i = blockIdx.x * 256 + threadIdx.x;
    if (i >= n8) return;
    const float4* p = (const float4*)in + (size_t)i * 2;
    float4 a = p[0], b = p[1];
    bf16x8 o;
    o[0] = (bf16_t)a.x; o[1] = (bf16_t)a.y; o[2] = (bf16_t)a.z; o[3] = (bf16_t)a.w;
    o[4] = (bf16_t)b.x; o[5] = (bf16_t)b.y; o[6] = (bf16_t)b.z; o[7] = (bf16_t)b.w;
    *((bf16x8*)out + i) = o;
}

// ---------- transpose + cast: W [1024][1024] fp32 [K][N] -> [N][K] bf16 ----------
__global__ __launch_bounds__(256) void transpose_cast(
    const float* __restrict__ W0, const float* __restrict__ W1,
    const float* __restrict__ W2, const float* __restrict__ W3,
    bf16_t* __restrict__ out)
{
    __shared__ float st[32][33];
    const float* W = (blockIdx.z == 0) ? W0 : (blockIdx.z == 1) ? W1
                   : (blockIdx.z == 2) ? W2 : W3;
    bf16_t* o = out + (size_t)blockIdx.z * 1024 * 1024;
    const int n0 = blockIdx.x * 32, k0 = blockIdx.y * 32;
    const int t = threadIdx.x;
    const int r = t >> 3, c4 = (t & 7) * 4;
    float4 v = *(const float4*)(W + (size_t)(k0 + r) * 1024 + n0 + c4);
    st[r][c4 + 0] = v.x; st[r][c4 + 1] = v.y; st[r][c4 + 2] = v.z; st[r][c4 + 3] = v.w;
    __syncthreads();
    bf16_t tmp[4] __attribute__((aligned(8)));
    #pragma unroll
    for (int i = 0; i < 4; ++i) tmp[i] = (bf16_t)st[c4 + i][r];
    *(uint2*)(o + (size_t)(n0 + r) * 1024 + k0 + c4) = *(const uint2*)tmp;
}

// ---------- MFMA GEMM: C = A[M,1024] @ Bt[N,1024]^T + bias ----------
template<bool FUSED, int MT>
__global__ __launch_bounds__(256, 3) void gemm_glds(
    const bf16_t* __restrict__ A, const bf16_t* __restrict__ Bt,
    const float* __restrict__ b0, const float* __restrict__ b1,
    const float* __restrict__ b2,
    bf16_t* __restrict__ Qo, bf16_t* __restrict__ Ko, bf16_t* __restrict__ Vo,
    float* __restrict__ Fo)
{
    const int K = 1024;
    __shared__ __align__(16) bf16_t As[MT * 32];
    __shared__ __align__(16) bf16_t Bs[128 * 32];

    constexpr int NTPW = (MT == 128) ? 4 : 2;
    constexpr int JA   = MT / 64;

    const int tid  = threadIdx.x;
    const int wave = tid >> 6;
    const int lane = tid & 63;
    const int quad = lane >> 4;
    const int l16  = lane & 15;
    const int m0 = blockIdx.y * MT;
    const int n0 = blockIdx.x * 128;
    const int wm = (MT == 128) ? (wave >> 1) * 64 : 0;
    const int wn = (MT == 128) ? (wave & 1) * 64 : wave * 32;

    int goffA[JA], goffB[2];
    #pragma unroll
    for (int j = 0; j < JA; ++j) {
        const int row = j * 64 + (tid >> 2);
        const int cl  = (tid & 3) ^ ((row >> 1) & 3);
        goffA[j] = (m0 + row) * K + cl * 8;
    }
    #pragma unroll
    for (int j = 0; j < 2; ++j) {
        const int row = j * 64 + (tid >> 2);
        const int cl  = (tid & 3) ^ ((row >> 1) & 3);
        goffB[j] = (n0 + row) * K + cl * 8;
    }
    const int ldsoff = wave * 1024;

    f32x4 acc[4][NTPW] = {};
    const int sw = (l16 >> 1) & 3;

    for (int k0 = 0; k0 < K; k0 += 32) {
        #pragma unroll
        for (int j = 0; j < JA; ++j)
            async16(A + goffA[j] + k0, (char*)As + j * 4096 + ldsoff);
        #pragma unroll
        for (int j = 0; j < 2; ++j)
            async16(Bt + goffB[j] + k0, (char*)Bs + j * 4096 + ldsoff);
        __syncthreads();

        bf16x8 af[4], bfr[NTPW];
        #pragma unroll
        for (int mt = 0; mt < 4; ++mt)
            af[mt] = *(const bf16x8*)(&As[(wm + mt * 16 + l16) * 32 + (quad ^ sw) * 8]);
        #pragma unroll
        for (int nt = 0; nt < NTPW; ++nt)
            bfr[nt] = *(const bf16x8*)(&Bs[(wn + nt * 16 + l16) * 32 + (quad ^ sw) * 8]);
        #pragma unroll
        for (int mt = 0; mt < 4; ++mt)
            #pragma unroll
            for (int nt = 0; nt < NTPW; ++nt)
                acc[mt][nt] = __builtin_amdgcn_mfma_f32_16x16x32_bf16(
                    af[mt], bfr[nt], acc[mt][nt], 0, 0, 0);
        __syncthreads();
    }

    if (FUSED) {
        const int sel = n0 >> 10;
        const float* bias = (sel == 0) ? b0 : (sel == 1) ? b1 : b2;
        bf16_t* Cout      = (sel == 0) ? Qo : (sel == 1) ? Ko : Vo;
        const float scl   = (sel == 1) ? SCALE_LOG2E : 1.0f;
        const int nb = n0 & 1023;
        #pragma unroll
        for (int nt = 0; nt < NTPW; ++nt) {
            const int n = nb + wn + nt * 16 + l16;
            const float bb = bias[n];
            #pragma unroll
            for (int mt = 0; mt < 4; ++mt)
                #pragma unroll
                for (int i = 0; i < 4; ++i) {
                    const int m = m0 + wm + mt * 16 + quad * 4 + i;
                    Cout[(size_t)m * 1024 + n] = (bf16_t)((acc[mt][nt][i] + bb) * scl);
                }
        }
    } else {
        #pragma unroll
        for (int nt = 0; nt < NTPW; ++nt) {
            const int n = n0 + wn + nt * 16 + l16;
            const float bb = b0[n];
            #pragma unroll
            for (int mt = 0; mt < 4; ++mt)
                #pragma unroll
                for (int i = 0; i < 4; ++i) {
                    const int m = m0 + wm + mt * 16 + quad * 4 + i;
                    Fo[(size_t)m * 1024 + n] = acc[mt][nt][i] + bb;
                }
        }
    }
}

// ---------- MFMA flash attention, register-path P (no LDS round-trip) ----------
// Grid 1024: (head hd = bx>>2, q-chunk qc = bx&3). 256 thr = 4 waves, wave
// owns 64 q rows (4 q-subs of 16). K pre-scaled by 0.125*log2e.
// S^T = K.Q^T (swap operands): C-layout of S^T gives lane q=l16, keys=quad*4+i
// == B-operand layout of v_mfma_f32_16x16x16_bf16. p = exp2(s) packed
// in-register (2 v_perm) feeds Z^T = V^T.P^T and l = 1.P^T directly.
// j-loop is FULLY UNROLLED: double-buffer indices are compile-time, so
// kf[][] stays in VGPRs (runtime-indexed reg arrays spill to scratch -- this
// was round 6's 5x regression: 497 MB scratch WRITE_SIZE).
__global__ __launch_bounds__(256, 4) void attn_kernel(
    const bf16_t* __restrict__ Q, const bf16_t* __restrict__ K,
    const bf16_t* __restrict__ V, bf16_t* __restrict__ Z)
{
    __shared__ __align__(16) bf16_t Vt[2][16 * 72];   // [buf][d][key], stride 72

    const int tid  = threadIdx.x;
    const int wave = tid >> 6;
    const int lane = tid & 63;
    const int quad = lane >> 4;
    const int l16  = lane & 15;
    const int hd = blockIdx.x >> 2;
    const int qc = blockIdx.x & 3;
    const int a = hd >> 2, b = hd & 3;
    const int col0 = a * 16;
    const int qbase = qc * 256 + wave * 64;

    // Q as B-operand of S^T: B[n=q=l16][k=d=quad*8+j], quads 2,3 zero (d<16)
    bf16x8 qf[4] = {};
    if (quad < 2) {
        #pragma unroll
        for (int qs = 0; qs < 4; ++qs)
            qf[qs] = *(const bf16x8*)(Q +
                (size_t)(b * 1024 + qbase + qs * 16 + l16) * 1024 + col0 + quad * 8);
    }

    // K as A-operand of S^T: A[m=key=l16][k=d=quad*8+j], double-buffered regs
    const bf16_t* Kp = K + (size_t)(b * 1024 + l16) * 1024 + col0 + quad * 8;
    bf16x8 kf[2][4] = {};
    if (quad < 2) {
        #pragma unroll
        for (int kt = 0; kt < 4; ++kt)
            kf[0][kt] = *(const bf16x8*)(Kp + (size_t)(kt * 16) * 1024);
    }

    // V staging: thread (r = tid>>2, dq = (tid&3)*4) loads V[r][dq..dq+3],
    // writes transposed Vt[dq+ii][r].
    const int r  = tid >> 2;
    const int dq = (tid & 3) * 4;
    const bf16_t* Vp = V + (size_t)(b * 1024 + r) * 1024 + col0 + dq;

    uint2 vv = *(const uint2*)Vp;          // tile 0
    {
        bf16_t t4[4] __attribute__((aligned(8)));
        *(uint2*)t4 = vv;
        #pragma unroll
        for (int ii = 0; ii < 4; ++ii)
            Vt[0][(dq + ii) * 72 + r] = t4[ii];
    }
    vv = *(const uint2*)(Vp + (size_t)64 * 1024);   // prefetch tile 1
    __syncthreads();

    const s16x4 ones = { 0x3F80, 0x3F80, 0x3F80, 0x3F80 };  // bf16 1.0 x4

    f32x4 zacc[4] = {};
    f32x4 lacc[4] = {};

    #pragma unroll   // FULL unroll: cur/nxt compile-time -> kf stays in VGPRs
    for (int j = 0; j < 16; ++j) {
        const int cur = j & 1, nxt = cur ^ 1;

        // prefetch K frags for tile j+1
        if (j < 15 && quad < 2) {
            #pragma unroll
            for (int kt = 0; kt < 4; ++kt)
                kf[nxt][kt] = *(const bf16x8*)(Kp + (size_t)((j + 1) * 64 + kt * 16) * 1024);
        }
        // stage V tile j+1 into Vt[nxt]; prefetch V tile j+2
        if (j < 15) {
            bf16_t t4[4] __attribute__((aligned(8)));
            *(uint2*)t4 = vv;
            #pragma unroll
            for (int ii = 0; ii < 4; ++ii)
                Vt[nxt][(dq + ii) * 72 + r] = t4[ii];
            if (j < 14)
                vv = *(const uint2*)(Vp + (size_t)((j + 2) * 64) * 1024);
        }

        // compute on tile j
        #pragma unroll
        for (int kt = 0; kt < 4; ++kt) {
            // V^T A-frag: A[m=d=l16][k=key=quad*4+jj]
            const s16x4 vfrag = __builtin_bit_cast(s16x4,
                *(const uint2*)(&Vt[cur][l16 * 72 + kt * 16 + quad * 4]));
            #pragma unroll
            for (int qs = 0; qs < 4; ++qs) {
                f32x4 zc = {0.f, 0.f, 0.f, 0.f};
                f32x4 s = __builtin_amdgcn_mfma_f32_16x16x32_bf16(
                    kf[cur][kt], qf[qs], zc, 0, 0, 0);
                unsigned int u0 = __builtin_bit_cast(unsigned int, exp2f(s[0])) + 0x8000u;
                unsigned int u1 = __builtin_bit_cast(unsigned int, exp2f(s[1])) + 0x8000u;
                unsigned int u2 = __builtin_bit_cast(unsigned int, exp2f(s[2])) + 0x8000u;
                unsigned int u3 = __builtin_bit_cast(unsigned int, exp2f(s[3])) + 0x8000u;
                uint2 w;
                w.x = __builtin_amdgcn_perm(u1, u0, 0x07060302u);  // [bf16(p1)|bf16(p0)]
                w.y = __builtin_amdgcn_perm(u3, u2, 0x07060302u);
                const s16x4 pfrag = __builtin_bit_cast(s16x4, w);
                zacc[qs] = __builtin_amdgcn_mfma_f32_16x16x16bf16_1k(
                    vfrag, pfrag, zacc[qs], 0, 0, 0);
                lacc[qs] = __builtin_amdgcn_mfma_f32_16x16x16bf16_1k(
                    ones, pfrag, lacc[qs], 0, 0, 0);
            }
        }
        __syncthreads();
    }

    // epilogue: lane holds Z^T[d=quad*4+i][q=l16] and l[q] in lacc[qs][*]
    #pragma unroll
    for (int qs = 0; qs < 4; ++qs) {
        const float inv = 1.0f / lacc[qs][0];
        const int q = qbase + qs * 16 + l16;
        bf16_t o4[4] __attribute__((aligned(8)));
        #pragma unroll
        for (int i = 0; i < 4; ++i) o4[i] = (bf16_t)(zacc[qs][i] * inv);
        *(uint2*)(Z + ((size_t)hd * 1024 + q) * 16 + quad * 4) = *(const uint2*)o4;
    }
}

extern "C" void kernel_launch(void* const* d_in, const int* in_sizes, int n_in,
                              void* d_out, int out_size, void* d_ws, size_t ws_size,
                              hipStream_t stream) {
    const float* x  = (const float*)d_in[0];
    const float* Wq = (const float*)d_in[1];
    const float* bq = (const float*)d_in[2];
    const float* Wk = (const float*)d_in[3];
    const float* bk = (const float*)d_in[4];
    const float* Wv = (const float*)d_in[5];
    const float* bv = (const float*)d_in[6];
    const float* Wo = (const float*)d_in[7];
    const float* bo = (const float*)d_in[8];
    float* out = (float*)d_out;

    char* ws = (char*)d_ws;
    bf16_t* x_bf = (bf16_t*)(ws);
    bf16_t* Wt   = (bf16_t*)(ws + (8u << 20));   // q|k|v|o slabs, contiguous
    bf16_t* Qb   = (bf16_t*)(ws + (16u << 20));
    bf16_t* Kb   = (bf16_t*)(ws + (24u << 20));
    bf16_t* Vb   = (bf16_t*)(ws + (32u << 20));
    bf16_t* Zb   = (bf16_t*)(ws + (40u << 20));
    bf16_t* WtO  = Wt + (size_t)3 * 1024 * 1024;

    cast_f32_bf16<<<dim3(2048), dim3(256), 0, stream>>>(x, x_bf, 524288);
    transpose_cast<<<dim3(32, 32, 4), dim3(256), 0, stream>>>(Wq, Wk, Wv, Wo, Wt);

    // fused QKV: Bt = [3072][1024] (Wq|Wk|Wv)
    gemm_glds<true, 128><<<dim3(24, 32), dim3(256), 0, stream>>>(
        x_bf, Wt, bq, bk, bv, Qb, Kb, Vb, nullptr);

    attn_kernel<<<dim3(1024), dim3(256), 0, stream>>>(Qb, Kb, Vb, Zb);

    // O-projection: 64x128 tiles -> 512 blocks (2/CU)
    gemm_glds<false, 64><<<dim3(8, 64), dim3(256), 0, stream>>>(
        Zb, WtO, bo, nullptr, nullptr, nullptr, nullptr, nullptr, out);
}

// Round 8
// 191.227 us; speedup vs baseline: 9.7898x; 1.1646x over previous
//
#include <hip/hip_runtime.h>
#include <hip/hip_bf16.h>

// B=4, T=1024, E=1024, ATT=64, NH=16, AH=1024. M = B*T = 4096, K = N = 1024.
// Pipeline: cast x->bf16; transpose+cast W{q,k,v,o} -> [N][K] bf16;
//           fused QKV MFMA GEMM (128x128, global_load_lds, K-slab pre-scaled
//           by 0.125*log2e); register-path MFMA flash attention (S^T trick,
//           HW v_exp_f32); O-proj GEMM (64x128 -> 512 blocks).

typedef __bf16 bf16_t;
typedef bf16_t bf16x8 __attribute__((ext_vector_type(8)));
typedef short  s16x4 __attribute__((ext_vector_type(4)));
typedef float  f32x4 __attribute__((ext_vector_type(4)));

#define SCALE_LOG2E 0.18033688011112042f  /* 0.125 * log2(e) */

__device__ __forceinline__ void async16(const bf16_t* g, void* l) {
    __builtin_amdgcn_global_load_lds(
        (const __attribute__((address_space(1))) unsigned int*)g,
        (__attribute__((address_space(3))) unsigned int*)l,
        16, 0, 0);
}

// ---------- cast fp32 -> bf16, 8 elems/thread ----------
__global__ __launch_bounds__(256) void cast_f32_bf16(
    const float* __restrict__ in, bf16_t* __restrict__ out, int n8)
{
    int i = blockIdx.x * 256 + threadIdx.x;
    if (i >= n8) return;
    const float4* p = (const float4*)in + (size_t)i * 2;
    float4 a = p[0], b = p[1];
    bf16x8 o;
    o[0] = (bf16_t)a.x; o[1] = (bf16_t)a.y; o[2] = (bf16_t)a.z; o[3] = (bf16_t)a.w;
    o[4] = (bf16_t)b.x; o[5] = (bf16_t)b.y; o[6] = (bf16_t)b.z; o[7] = (bf16_t)b.w;
    *((bf16x8*)out + i) = o;
}

// ---------- transpose + cast: W [1024][1024] fp32 [K][N] -> [N][K] bf16 ----------
__global__ __launch_bounds__(256) void transpose_cast(
    const float* __restrict__ W0, const float* __restrict__ W1,
    const float* __restrict__ W2, const float* __restrict__ W3,
    bf16_t* __restrict__ out)
{
    __shared__ float st[32][33];
    const float* W = (blockIdx.z == 0) ? W0 : (blockIdx.z == 1) ? W1
                   : (blockIdx.z == 2) ? W2 : W3;
    bf16_t* o = out + (size_t)blockIdx.z * 1024 * 1024;
    const int n0 = blockIdx.x * 32, k0 = blockIdx.y * 32;
    const int t = threadIdx.x;
    const int r = t >> 3, c4 = (t & 7) * 4;
    float4 v = *(const float4*)(W + (size_t)(k0 + r) * 1024 + n0 + c4);
    st[r][c4 + 0] = v.x; st[r][c4 + 1] = v.y; st[r][c4 + 2] = v.z; st[r][c4 + 3] = v.w;
    __syncthreads();
    bf16_t tmp[4] __attribute__((aligned(8)));
    #pragma unroll
    for (int i = 0; i < 4; ++i) tmp[i] = (bf16_t)st[c4 + i][r];
    *(uint2*)(o + (size_t)(n0 + r) * 1024 + k0 + c4) = *(const uint2*)tmp;
}

// ---------- MFMA GEMM: C = A[M,1024] @ Bt[N,1024]^T + bias ----------
template<bool FUSED, int MT>
__global__ __launch_bounds__(256, 3) void gemm_glds(
    const bf16_t* __restrict__ A, const bf16_t* __restrict__ Bt,
    const float* __restrict__ b0, const float* __restrict__ b1,
    const float* __restrict__ b2,
    bf16_t* __restrict__ Qo, bf16_t* __restrict__ Ko, bf16_t* __restrict__ Vo,
    float* __restrict__ Fo)
{
    const int K = 1024;
    __shared__ __align__(16) bf16_t As[MT * 32];
    __shared__ __align__(16) bf16_t Bs[128 * 32];

    constexpr int NTPW = (MT == 128) ? 4 : 2;
    constexpr int JA   = MT / 64;

    const int tid  = threadIdx.x;
    const int wave = tid >> 6;
    const int lane = tid & 63;
    const int quad = lane >> 4;
    const int l16  = lane & 15;
    const int m0 = blockIdx.y * MT;
    const int n0 = blockIdx.x * 128;
    const int wm = (MT == 128) ? (wave >> 1) * 64 : 0;
    const int wn = (MT == 128) ? (wave & 1) * 64 : wave * 32;

    int goffA[JA], goffB[2];
    #pragma unroll
    for (int j = 0; j < JA; ++j) {
        const int row = j * 64 + (tid >> 2);
        const int cl  = (tid & 3) ^ ((row >> 1) & 3);
        goffA[j] = (m0 + row) * K + cl * 8;
    }
    #pragma unroll
    for (int j = 0; j < 2; ++j) {
        const int row = j * 64 + (tid >> 2);
        const int cl  = (tid & 3) ^ ((row >> 1) & 3);
        goffB[j] = (n0 + row) * K + cl * 8;
    }
    const int ldsoff = wave * 1024;

    f32x4 acc[4][NTPW] = {};
    const int sw = (l16 >> 1) & 3;

    for (int k0 = 0; k0 < K; k0 += 32) {
        #pragma unroll
        for (int j = 0; j < JA; ++j)
            async16(A + goffA[j] + k0, (char*)As + j * 4096 + ldsoff);
        #pragma unroll
        for (int j = 0; j < 2; ++j)
            async16(Bt + goffB[j] + k0, (char*)Bs + j * 4096 + ldsoff);
        __syncthreads();

        bf16x8 af[4], bfr[NTPW];
        #pragma unroll
        for (int mt = 0; mt < 4; ++mt)
            af[mt] = *(const bf16x8*)(&As[(wm + mt * 16 + l16) * 32 + (quad ^ sw) * 8]);
        #pragma unroll
        for (int nt = 0; nt < NTPW; ++nt)
            bfr[nt] = *(const bf16x8*)(&Bs[(wn + nt * 16 + l16) * 32 + (quad ^ sw) * 8]);
        #pragma unroll
        for (int mt = 0; mt < 4; ++mt)
            #pragma unroll
            for (int nt = 0; nt < NTPW; ++nt)
                acc[mt][nt] = __builtin_amdgcn_mfma_f32_16x16x32_bf16(
                    af[mt], bfr[nt], acc[mt][nt], 0, 0, 0);
        __syncthreads();
    }

    if (FUSED) {
        const int sel = n0 >> 10;
        const float* bias = (sel == 0) ? b0 : (sel == 1) ? b1 : b2;
        bf16_t* Cout      = (sel == 0) ? Qo : (sel == 1) ? Ko : Vo;
        const float scl   = (sel == 1) ? SCALE_LOG2E : 1.0f;
        const int nb = n0 & 1023;
        #pragma unroll
        for (int nt = 0; nt < NTPW; ++nt) {
            const int n = nb + wn + nt * 16 + l16;
            const float bb = bias[n];
            #pragma unroll
            for (int mt = 0; mt < 4; ++mt)
                #pragma unroll
                for (int i = 0; i < 4; ++i) {
                    const int m = m0 + wm + mt * 16 + quad * 4 + i;
                    Cout[(size_t)m * 1024 + n] = (bf16_t)((acc[mt][nt][i] + bb) * scl);
                }
        }
    } else {
        #pragma unroll
        for (int nt = 0; nt < NTPW; ++nt) {
            const int n = n0 + wn + nt * 16 + l16;
            const float bb = b0[n];
            #pragma unroll
            for (int mt = 0; mt < 4; ++mt)
                #pragma unroll
                for (int i = 0; i < 4; ++i) {
                    const int m = m0 + wm + mt * 16 + quad * 4 + i;
                    Fo[(size_t)m * 1024 + n] = acc[mt][nt][i] + bb;
                }
        }
    }
}

// ---------- MFMA flash attention, register-path P, HW exp ----------
// Grid 1024: (head hd = bx>>2, q-chunk qc = bx&3). 256 thr = 4 waves, wave
// owns 64 q rows (4 q-subs of 16). K pre-scaled by 0.125*log2e.
// S^T = K.Q^T (swap operands): C-layout of S^T gives lane q=l16, keys=quad*4+i
// == B-operand layout of v_mfma_f32_16x16x16_bf16. p = exp2(s) packed
// in-register (2 v_perm) feeds Z^T = V^T.P^T and l = 1.P^T directly.
// exp via __builtin_amdgcn_exp2f = bare v_exp_f32 (plain exp2f lowers to the
// libm __ocml_exp2_f32 expansion, ~15 VALU/score -- that was the invariant
// pinning attn at ~89us across rounds 4-7). j-loop fully unrolled so
// double-buffer regs stay in VGPRs (round 6: runtime-indexed reg array
// spilled to scratch, 497 MB WRITE_SIZE).
__global__ __launch_bounds__(256, 4) void attn_kernel(
    const bf16_t* __restrict__ Q, const bf16_t* __restrict__ K,
    const bf16_t* __restrict__ V, bf16_t* __restrict__ Z)
{
    __shared__ __align__(16) bf16_t Vt[2][16 * 72];   // [buf][d][key], stride 72

    const int tid  = threadIdx.x;
    const int wave = tid >> 6;
    const int lane = tid & 63;
    const int quad = lane >> 4;
    const int l16  = lane & 15;
    const int hd = blockIdx.x >> 2;
    const int qc = blockIdx.x & 3;
    const int a = hd >> 2, b = hd & 3;
    const int col0 = a * 16;
    const int qbase = qc * 256 + wave * 64;

    // Q as B-operand of S^T: B[n=q=l16][k=d=quad*8+j], quads 2,3 zero (d<16)
    bf16x8 qf[4] = {};
    if (quad < 2) {
        #pragma unroll
        for (int qs = 0; qs < 4; ++qs)
            qf[qs] = *(const bf16x8*)(Q +
                (size_t)(b * 1024 + qbase + qs * 16 + l16) * 1024 + col0 + quad * 8);
    }

    // K as A-operand of S^T: A[m=key=l16][k=d=quad*8+j], double-buffered regs
    const bf16_t* Kp = K + (size_t)(b * 1024 + l16) * 1024 + col0 + quad * 8;
    bf16x8 kf[2][4] = {};
    if (quad < 2) {
        #pragma unroll
        for (int kt = 0; kt < 4; ++kt)
            kf[0][kt] = *(const bf16x8*)(Kp + (size_t)(kt * 16) * 1024);
    }

    // V staging: thread (r = tid>>2, dq = (tid&3)*4) loads V[r][dq..dq+3],
    // writes transposed Vt[dq+ii][r].
    const int r  = tid >> 2;
    const int dq = (tid & 3) * 4;
    const bf16_t* Vp = V + (size_t)(b * 1024 + r) * 1024 + col0 + dq;

    uint2 vv = *(const uint2*)Vp;          // tile 0
    {
        bf16_t t4[4] __attribute__((aligned(8)));
        *(uint2*)t4 = vv;
        #pragma unroll
        for (int ii = 0; ii < 4; ++ii)
            Vt[0][(dq + ii) * 72 + r] = t4[ii];
    }
    vv = *(const uint2*)(Vp + (size_t)64 * 1024);   // prefetch tile 1
    __syncthreads();

    const s16x4 ones = { 0x3F80, 0x3F80, 0x3F80, 0x3F80 };  // bf16 1.0 x4

    f32x4 zacc[4] = {};
    f32x4 lacc[4] = {};

    #pragma unroll   // FULL unroll: cur/nxt compile-time -> kf stays in VGPRs
    for (int j = 0; j < 16; ++j) {
        const int cur = j & 1, nxt = cur ^ 1;

        // prefetch K frags for tile j+1
        if (j < 15 && quad < 2) {
            #pragma unroll
            for (int kt = 0; kt < 4; ++kt)
                kf[nxt][kt] = *(const bf16x8*)(Kp + (size_t)((j + 1) * 64 + kt * 16) * 1024);
        }
        // stage V tile j+1 into Vt[nxt]; prefetch V tile j+2
        if (j < 15) {
            bf16_t t4[4] __attribute__((aligned(8)));
            *(uint2*)t4 = vv;
            #pragma unroll
            for (int ii = 0; ii < 4; ++ii)
                Vt[nxt][(dq + ii) * 72 + r] = t4[ii];
            if (j < 14)
                vv = *(const uint2*)(Vp + (size_t)((j + 2) * 64) * 1024);
        }

        // compute on tile j
        #pragma unroll
        for (int kt = 0; kt < 4; ++kt) {
            // V^T A-frag: A[m=d=l16][k=key=quad*4+jj]
            const s16x4 vfrag = __builtin_bit_cast(s16x4,
                *(const uint2*)(&Vt[cur][l16 * 72 + kt * 16 + quad * 4]));
            #pragma unroll
            for (int qs = 0; qs < 4; ++qs) {
                f32x4 zc = {0.f, 0.f, 0.f, 0.f};
                f32x4 s = __builtin_amdgcn_mfma_f32_16x16x32_bf16(
                    kf[cur][kt], qf[qs], zc, 0, 0, 0);
                unsigned int u0 = __builtin_bit_cast(unsigned int,
                    __builtin_amdgcn_exp2f(s[0])) + 0x8000u;
                unsigned int u1 = __builtin_bit_cast(unsigned int,
                    __builtin_amdgcn_exp2f(s[1])) + 0x8000u;
                unsigned int u2 = __builtin_bit_cast(unsigned int,
                    __builtin_amdgcn_exp2f(s[2])) + 0x8000u;
                unsigned int u3 = __builtin_bit_cast(unsigned int,
                    __builtin_amdgcn_exp2f(s[3])) + 0x8000u;
                uint2 w;
                w.x = __builtin_amdgcn_perm(u1, u0, 0x07060302u);  // [bf16(p1)|bf16(p0)]
                w.y = __builtin_amdgcn_perm(u3, u2, 0x07060302u);
                const s16x4 pfrag = __builtin_bit_cast(s16x4, w);
                zacc[qs] = __builtin_amdgcn_mfma_f32_16x16x16bf16_1k(
                    vfrag, pfrag, zacc[qs], 0, 0, 0);
                lacc[qs] = __builtin_amdgcn_mfma_f32_16x16x16bf16_1k(
                    ones, pfrag, lacc[qs], 0, 0, 0);
            }
        }
        __syncthreads();
    }

    // epilogue: lane holds Z^T[d=quad*4+i][q=l16] and l[q] in lacc[qs][*]
    #pragma unroll
    for (int qs = 0; qs < 4; ++qs) {
        const float inv = 1.0f / lacc[qs][0];
        const int q = qbase + qs * 16 + l16;
        bf16_t o4[4] __attribute__((aligned(8)));
        #pragma unroll
        for (int i = 0; i < 4; ++i) o4[i] = (bf16_t)(zacc[qs][i] * inv);
        *(uint2*)(Z + ((size_t)hd * 1024 + q) * 16 + quad * 4) = *(const uint2*)o4;
    }
}

extern "C" void kernel_launch(void* const* d_in, const int* in_sizes, int n_in,
                              void* d_out, int out_size, void* d_ws, size_t ws_size,
                              hipStream_t stream) {
    const float* x  = (const float*)d_in[0];
    const float* Wq = (const float*)d_in[1];
    const float* bq = (const float*)d_in[2];
    const float* Wk = (const float*)d_in[3];
    const float* bk = (const float*)d_in[4];
    const float* Wv = (const float*)d_in[5];
    const float* bv = (const float*)d_in[6];
    const float* Wo = (const float*)d_in[7];
    const float* bo = (const float*)d_in[8];
    float* out = (float*)d_out;

    char* ws = (char*)d_ws;
    bf16_t* x_bf = (bf16_t*)(ws);
    bf16_t* Wt   = (bf16_t*)(ws + (8u << 20));   // q|k|v|o slabs, contiguous
    bf16_t* Qb   = (bf16_t*)(ws + (16u << 20));
    bf16_t* Kb   = (bf16_t*)(ws + (24u << 20));
    bf16_t* Vb   = (bf16_t*)(ws + (32u << 20));
    bf16_t* Zb   = (bf16_t*)(ws + (40u << 20));
    bf16_t* WtO  = Wt + (size_t)3 * 1024 * 1024;

    cast_f32_bf16<<<dim3(2048), dim3(256), 0, stream>>>(x, x_bf, 524288);
    transpose_cast<<<dim3(32, 32, 4), dim3(256), 0, stream>>>(Wq, Wk, Wv, Wo, Wt);

    // fused QKV: Bt = [3072][1024] (Wq|Wk|Wv)
    gemm_glds<true, 128><<<dim3(24, 32), dim3(256), 0, stream>>>(
        x_bf, Wt, bq, bk, bv, Qb, Kb, Vb, nullptr);

    attn_kernel<<<dim3(1024), dim3(256), 0, stream>>>(Qb, Kb, Vb, Zb);

    // O-projection: 64x128 tiles -> 512 blocks (2/CU)
    gemm_glds<false, 64><<<dim3(8, 64), dim3(256), 0, stream>>>(
        Zb, WtO, bo, nullptr, nullptr, nullptr, nullptr, nullptr, out);
}